// Round 1
// 2046.906 us; speedup vs baseline: 1.1697x; 1.1697x over previous
//
#include <hip/hip_runtime.h>

// Problem constants (match reference)
#define NN 50000
#define EE 800000
#define ND 64
#define ED 64
#define HD 192
#define AS 196   // LDS activation row stride in floats (192 + 4; %32==4 -> max 2-way bank aliasing, free)

typedef short s16x8 __attribute__((ext_vector_type(8)));
typedef float f32x4 __attribute__((ext_vector_type(4)));

#define MFMA16 __builtin_amdgcn_mfma_f32_16x16x32_bf16

// ---------- numeric helpers ----------
__device__ __forceinline__ unsigned short bf16rn(float x) {
  unsigned u = __float_as_uint(x);
  return (unsigned short)((u + 0x7fffu + ((u >> 16) & 1u)) >> 16);
}

// Split 8 consecutive fp32 into hi/lo bf16 fragments (fp32-accurate 2-term representation).
__device__ __forceinline__ void split8(const float* p, s16x8& hi, s16x8& lo) {
  f32x4 a = *(const f32x4*)p;
  f32x4 b = *(const f32x4*)(p + 4);
#pragma unroll
  for (int j = 0; j < 4; ++j) {
    unsigned short h = bf16rn(a[j]);
    float hf = __uint_as_float(((unsigned)h) << 16);
    unsigned short l = bf16rn(a[j] - hf);
    hi[j] = (short)h; lo[j] = (short)l;
  }
#pragma unroll
  for (int j = 0; j < 4; ++j) {
    unsigned short h = bf16rn(b[j]);
    float hf = __uint_as_float(((unsigned)h) << 16);
    unsigned short l = bf16rn(b[j] - hf);
    hi[4 + j] = (short)h; lo[4 + j] = (short)l;
  }
}

__device__ __forceinline__ float fsigmoid(float x) { return 1.f / (1.f + __expf(-x)); }
__device__ __forceinline__ float ftanh(float x) {
  const float ax = fabsf(x);
  const float t = __expf(2.f * ax);
  const float r = 1.f - 2.f / (t + 1.f);
  return x >= 0.f ? r : -r;
}

// ---------- GEMM core ----------
// D += A * W^T using split-bf16 (3 MFMAs per k-slab: ah*bh + al*bh + ah*bl).
// A-frag: lane holds A[row = lane&15][k = ks*32 + (lane>>4)*8 + j]
// B pack: pack[((nt*KS+ks)*64 + lane)*8 + j] = W[nt*16 + (lane&15)][ks*32 + (lane>>4)*8 + j]
// hi plane at offset 0, lo plane at offset NTOT*KS*512 (NTOT = full-matrix NT; pass pack +
// nt0*KS*512 to run a sub-slice of N — the relative lo-plane offset stays NTOT*KS*512).
template <int NT, int KS, int NTOT = NT>
__device__ __forceinline__ void gemm3p(f32x4* acc, const s16x8* ah, const s16x8* al,
                                       const unsigned short* __restrict__ pack, int lane) {
  const int HOFF = NTOT * KS * 512;
#pragma unroll
  for (int ks = 0; ks < KS; ++ks) {
#pragma unroll
    for (int nt = 0; nt < NT; ++nt) {
      const unsigned short* bp = pack + ((nt * KS + ks) * 64 + lane) * 8;
      s16x8 bh = *(const s16x8*)bp;
      s16x8 bl = *(const s16x8*)(bp + HOFF);
      acc[nt] = MFMA16(ah[ks], bh, acc[nt], 0, 0, 0);
      acc[nt] = MFMA16(al[ks], bh, acc[nt], 0, 0, 0);
      acc[nt] = MFMA16(ah[ks], bl, acc[nt], 0, 0, 0);
    }
  }
}

// ---------- weight packing ----------
// order: 0 W1e(12,6,192) 1 W1n(12,8,256) 2 W2(12,6,192) 3 Wih_e(12,6,192) 4 Whh_e(12,2,64)
//        5 Wre(4,2,64)   6 Wih_a(12,6,192) 7 Whh_a(12,2,64) 8 Wra(4,2,64)
__global__ void k_pack(const float* __restrict__ w0, const float* __restrict__ w1,
                       const float* __restrict__ w2, const float* __restrict__ w3,
                       const float* __restrict__ w4, const float* __restrict__ w5,
                       const float* __restrict__ w6, const float* __restrict__ w7,
                       const float* __restrict__ w8, unsigned short* __restrict__ packs) {
  int gid = blockIdx.x * 256 + threadIdx.x;
  const float* w; int off, sz, KS, K, local;
  if      (gid <  36864) { w = w0; off = 0;      sz = 36864; KS = 6; K = 192; local = gid; }
  else if (gid <  86016) { w = w1; off = 73728;  sz = 49152; KS = 8; K = 256; local = gid - 36864; }
  else if (gid < 122880) { w = w2; off = 172032; sz = 36864; KS = 6; K = 192; local = gid - 86016; }
  else if (gid < 159744) { w = w3; off = 245760; sz = 36864; KS = 6; K = 192; local = gid - 122880; }
  else if (gid < 172032) { w = w4; off = 319488; sz = 12288; KS = 2; K = 64;  local = gid - 159744; }
  else if (gid < 176128) { w = w5; off = 344064; sz = 4096;  KS = 2; K = 64;  local = gid - 172032; }
  else if (gid < 212992) { w = w6; off = 352256; sz = 36864; KS = 6; K = 192; local = gid - 176128; }
  else if (gid < 225280) { w = w7; off = 425984; sz = 12288; KS = 2; K = 64;  local = gid - 212992; }
  else                   { w = w8; off = 450560; sz = 4096;  KS = 2; K = 64;  local = gid - 225280; }
  int j = local & 7;
  int lane = (local >> 3) & 63;
  int t = local >> 9;
  int ks = t % KS, nt = t / KS;
  int n = nt * 16 + (lane & 15);
  int k = ks * 32 + ((lane >> 4) & 3) * 8 + j;
  float v = w[n * K + k];
  unsigned short h = bf16rn(v);
  float hf = __uint_as_float(((unsigned)h) << 16);
  unsigned short l = bf16rn(v - hf);
  packs[off + local] = h;
  packs[off + sz + local] = l;
}

// ---------- CSR build ----------
__global__ void k_zero(int* __restrict__ cnt) {
  int i = blockIdx.x * 256 + threadIdx.x;
  if (i < NN) cnt[i] = 0;
}
__global__ void k_hist(const int* __restrict__ dst, int* __restrict__ cnt) {
  int e = blockIdx.x * 256 + threadIdx.x;
  if (e < EE) atomicAdd(&cnt[dst[e]], 1);
}
__global__ void k_scan(const int* __restrict__ cnt, int* __restrict__ roff, int* __restrict__ cursor) {
  __shared__ int sd[1024];
  const int tid = threadIdx.x;
  int carry = 0;
  for (int c = 0; c < 49; ++c) {
    const int idx = c * 1024 + tid;
    const int v = (idx < NN) ? cnt[idx] : 0;
    sd[tid] = v;
    __syncthreads();
    for (int off = 1; off < 1024; off <<= 1) {
      int t = (tid >= off) ? sd[tid - off] : 0;
      __syncthreads();
      sd[tid] += t;
      __syncthreads();
    }
    const int excl = carry + sd[tid] - v;
    if (idx < NN) { roff[idx] = excl; cursor[idx] = excl; }
    carry += sd[1023];
    __syncthreads();
  }
  if (tid == 0) roff[NN] = carry;
}
__global__ void k_scatter(const int* __restrict__ dst, int* __restrict__ cursor, int* __restrict__ elist) {
  int e = blockIdx.x * 256 + threadIdx.x;
  if (e < EE) {
    int p = atomicAdd(&cursor[dst[e]], 1);
    elist[p] = e;
  }
}

// ---------- edge kernel ----------
// 64 edges / block, 4 waves; wave w owns rows [w*16, w*16+16) at a SINGLE stride (AS) in every
// phase, so wave LDS regions are always disjoint. Barriers between phases are insurance only.
//
// R1 (this round): GRU r/z-gate accumulators FUSED (gi_rz += gh_rz in one accumulator array;
// only the n-gate keeps in/hn separate for the r*(hn+bhn) product). Accumulator peak drops
// 112 -> 80 regs, letting __launch_bounds__(256,3) hold 3 blocks/CU (LDS 3x50176 <= 160K);
// previous total VGPR+AGPR ~200 capped residency at 2 blocks/CU (Occupancy 23%).
__global__ __launch_bounds__(256, 3)
void edge_kernel(const float* __restrict__ nf, const float* __restrict__ efg,
                 const int* __restrict__ src, const int* __restrict__ dst,
                 const float* __restrict__ b1, const float* __restrict__ lng,
                 const float* __restrict__ lnb, const float* __restrict__ b2,
                 const float* __restrict__ bih, const float* __restrict__ bhh,
                 const float* __restrict__ bre,
                 const unsigned short* __restrict__ pW1, const unsigned short* __restrict__ pW2,
                 const unsigned short* __restrict__ pWih, const unsigned short* __restrict__ pWhh,
                 const unsigned short* __restrict__ pWre,
                 float* __restrict__ oute) {
  __shared__ float act[64 * AS];
  const int tid = threadIdx.x;
  const int e0 = blockIdx.x * 64;

  { // gather msg = [h_src | h_dst | e] into act (wave-local rows)
    const int r = tid >> 2, q = tid & 3;
    const int s = src[e0 + r];
    const int d = dst[e0 + r];
    const f32x4* nf4 = (const f32x4*)nf;
    const f32x4* ef4 = (const f32x4*)efg;
#pragma unroll
    for (int i = 0; i < 4; ++i) {
      const int c4 = q * 4 + i;
      *(f32x4*)&act[r * AS + c4 * 4]       = nf4[s * 16 + c4];
      *(f32x4*)&act[r * AS + 64 + c4 * 4]  = nf4[d * 16 + c4];
      *(f32x4*)&act[r * AS + 128 + c4 * 4] = ef4[(e0 + r) * 16 + c4];
    }
  }
  __syncthreads();

  const int w = tid >> 6, lane = tid & 63;
  const int quad = lane >> 4, lc = lane & 15;
  const int arow = w * 16 + lc;          // A-frag row
  const int obase = w * 16 + quad * 4;   // C/D-layout row base (+reg)
  const f32x4 vzero = {0.f, 0.f, 0.f, 0.f};

  s16x8 ah[6], al[6];
  f32x4 acc[12];

  // GEMM1: y = msg @ W1e^T + b1 -> LayerNorm -> leaky(0.2) -> act
#pragma unroll
  for (int ks = 0; ks < 6; ++ks) split8(&act[arow * AS + ks * 32 + quad * 8], ah[ks], al[ks]);
#pragma unroll
  for (int nt = 0; nt < 12; ++nt) acc[nt] = vzero;
  gemm3p<12, 6>(acc, ah, al, pW1, lane);
  {
    float s1[4] = {0, 0, 0, 0}, s2[4] = {0, 0, 0, 0};
#pragma unroll
    for (int nt = 0; nt < 12; ++nt) {
      const float bb = b1[nt * 16 + lc];
#pragma unroll
      for (int r = 0; r < 4; ++r) {
        const float v = acc[nt][r] + bb;
        acc[nt][r] = v; s1[r] += v; s2[r] += v * v;
      }
    }
#pragma unroll
    for (int r = 0; r < 4; ++r) {
#pragma unroll
      for (int m = 1; m < 16; m <<= 1) {
        s1[r] += __shfl_xor(s1[r], m, 16);
        s2[r] += __shfl_xor(s2[r], m, 16);
      }
      const float mu = s1[r] * (1.f / 192.f);
      const float va = s2[r] * (1.f / 192.f) - mu * mu;
      s1[r] = mu; s2[r] = rsqrtf(va + 1e-5f);
    }
#pragma unroll
    for (int nt = 0; nt < 12; ++nt) {
      const int col = nt * 16 + lc;
      const float g = lng[col], be = lnb[col];
#pragma unroll
      for (int r = 0; r < 4; ++r) {
        float v = (acc[nt][r] - s1[r]) * s2[r] * g + be;
        v = v > 0.f ? v : 0.2f * v;
        act[(obase + r) * AS + col] = v;
      }
    }
  }
  __syncthreads();

  // GEMM2: z = y @ W2^T + b2 -> act
#pragma unroll
  for (int ks = 0; ks < 6; ++ks) split8(&act[arow * AS + ks * 32 + quad * 8], ah[ks], al[ks]);
#pragma unroll
  for (int nt = 0; nt < 12; ++nt) acc[nt] = vzero;
  gemm3p<12, 6>(acc, ah, al, pW2, lane);
#pragma unroll
  for (int nt = 0; nt < 12; ++nt) {
    const int col = nt * 16 + lc;
    const float bb = b2[col];
#pragma unroll
    for (int r = 0; r < 4; ++r) act[(obase + r) * AS + col] = acc[nt][r] + bb;
  }
  __syncthreads();

  // GEMM3 (fused gates): rz = z @ Wih[0:128]^T + e @ Whh[0:128]^T (r,z gates sum directly);
  // ni = z @ Wih[128:192]^T, nh = e @ Whh[128:192]^T kept separate for r*(hn+bhn).
#pragma unroll
  for (int ks = 0; ks < 6; ++ks) split8(&act[arow * AS + ks * 32 + quad * 8], ah[ks], al[ks]);
  f32x4 rz[8], ni[4], nh[4], ro[4];
#pragma unroll
  for (int nt = 0; nt < 8; ++nt) rz[nt] = vzero;
#pragma unroll
  for (int nt = 0; nt < 4; ++nt) { ni[nt] = vzero; nh[nt] = vzero; ro[nt] = vzero; }
  gemm3p<8, 6, 12>(rz, ah, al, pWih, lane);
  gemm3p<4, 6, 12>(ni, ah, al, pWih + 8 * 6 * 512, lane);

  // e-side: gh parts + residual (A-frags straight from global edge_feats, L2-hot)
  s16x8 eh[2], el[2];
#pragma unroll
  for (int ks = 0; ks < 2; ++ks)
    split8(efg + (size_t)(e0 + arow) * ED + ks * 32 + quad * 8, eh[ks], el[ks]);
  gemm3p<8, 2, 12>(rz, eh, el, pWhh, lane);
  gemm3p<4, 2, 12>(nh, eh, el, pWhh + 8 * 2 * 512, lane);
  gemm3p<4, 2>(ro, eh, el, pWre, lane);

  // GRU + residual + leaky(0.01) -> update_edges
#pragma unroll
  for (int nt = 0; nt < 4; ++nt) {
    const int col = nt * 16 + lc;
    const float bir = bih[col], biz = bih[64 + col], bin = bih[128 + col];
    const float bhr = bhh[col], bhz = bhh[64 + col], bhn = bhh[128 + col];
    const float br = bre[col];
#pragma unroll
    for (int r = 0; r < 4; ++r) {
      const int row = obase + r;
      const float h = efg[(size_t)(e0 + row) * ED + col];
      const float rg = fsigmoid(rz[nt][r] + bir + bhr);
      const float zg = fsigmoid(rz[nt + 4][r] + biz + bhz);
      const float ng = ftanh(ni[nt][r] + bin + rg * (nh[nt][r] + bhn));
      float v = (1.f - zg) * ng + zg * h + ro[nt][r] + br;
      v = v > 0.f ? v : 0.01f * v;
      oute[(size_t)(e0 + row) * ED + col] = v;
    }
  }
}

// ---------- node kernel ----------
// 64 nodes / block, 4 waves. Every wave works inside its own 4096-float LDS window
// (act + w*4096) across ALL phases, so the stride-256 agg layout and stride-AS activation
// layout can never overlap another wave's region. LDS 64KB caps residency at 2 blocks/CU;
// same GRU-accumulator fusion applied for symmetry (identical math, fewer live AGPRs).
__global__ __launch_bounds__(256, 2)
void node_kernel(const float* __restrict__ nf,
                 const int* __restrict__ src,
                 const int* __restrict__ roff, const int* __restrict__ elist,
                 const float* __restrict__ b1, const float* __restrict__ lng,
                 const float* __restrict__ lnb, const float* __restrict__ b2,
                 const float* __restrict__ bih, const float* __restrict__ bhh,
                 const float* __restrict__ bra,
                 const unsigned short* __restrict__ pW1, const unsigned short* __restrict__ pW2,
                 const unsigned short* __restrict__ pWih, const unsigned short* __restrict__ pWhh,
                 const unsigned short* __restrict__ pWra,
                 const float* __restrict__ upd,
                 float* __restrict__ outn) {
  __shared__ float act[4 * 4096];  // 64 KB; one 4096-float window per wave
  const int tid = threadIdx.x;
  const int w = tid >> 6, lane = tid & 63;
  const int nb0 = blockIdx.x * 64;
  float* win = act + w * 4096;

  { // aggregation: window row i (node nb0 + w*16 + i) = [sum(128) | max(128)] at stride 256
    const int half = lane >> 5, c2 = (lane & 31) * 2;
#pragma unroll 1
    for (int i = 0; i < 16; ++i) {
      const int node = nb0 + w * 16 + i;
      float s0 = 0.f, s1v = 0.f;
      float m0 = -__builtin_inff(), m1 = -__builtin_inff();
      if (node < NN) {
        const int sidx = roff[node], eidx = roff[node + 1];
        int ix = sidx;
        for (; ix + 1 < eidx; ix += 2) {
          const int ea = elist[ix], eb = elist[ix + 1];
          const float* pa = half ? (upd + (size_t)ea * ED + c2) : (nf + (size_t)src[ea] * ND + c2);
          const float* pb = half ? (upd + (size_t)eb * ED + c2) : (nf + (size_t)src[eb] * ND + c2);
          const float a0 = pa[0], a1 = pa[1], c0 = pb[0], c1 = pb[1];
          s0 += a0 + c0; s1v += a1 + c1;
          m0 = fmaxf(m0, fmaxf(a0, c0)); m1 = fmaxf(m1, fmaxf(a1, c1));
        }
        if (ix < eidx) {
          const int ea = elist[ix];
          const float* pa = half ? (upd + (size_t)ea * ED + c2) : (nf + (size_t)src[ea] * ND + c2);
          const float a0 = pa[0], a1 = pa[1];
          s0 += a0; s1v += a1;
          m0 = fmaxf(m0, a0); m1 = fmaxf(m1, a1);
        }
        if (sidx == eidx) { m0 = 0.f; m1 = 0.f; }  // empty mailbox -> 0
      } else {
        m0 = 0.f; m1 = 0.f;  // tail rows: zero-fill (sum already 0)
      }
      const int cs = half * 64 + c2;
      win[i * 256 + cs] = s0;
      win[i * 256 + cs + 1] = s1v;
      win[i * 256 + 128 + cs] = m0;
      win[i * 256 + 128 + cs + 1] = m1;
    }
  }
  __syncthreads();

  const int quad = lane >> 4, lc = lane & 15;
  const f32x4 vzero = {0.f, 0.f, 0.f, 0.f};

  // GEMM1: y = agg(K=256) @ W1n^T + b1 -> LN -> leaky(0.2) -> window @ stride AS
  s16x8 ah8[8], al8[8];
#pragma unroll
  for (int ks = 0; ks < 8; ++ks) split8(&win[lc * 256 + ks * 32 + quad * 8], ah8[ks], al8[ks]);
  f32x4 acc[12];
#pragma unroll
  for (int nt = 0; nt < 12; ++nt) acc[nt] = vzero;
  gemm3p<12, 8>(acc, ah8, al8, pW1, lane);
  {
    float s1[4] = {0, 0, 0, 0}, s2[4] = {0, 0, 0, 0};
#pragma unroll
    for (int nt = 0; nt < 12; ++nt) {
      const float bb = b1[nt * 16 + lc];
#pragma unroll
      for (int r = 0; r < 4; ++r) {
        const float v = acc[nt][r] + bb;
        acc[nt][r] = v; s1[r] += v; s2[r] += v * v;
      }
    }
#pragma unroll
    for (int r = 0; r < 4; ++r) {
#pragma unroll
      for (int m = 1; m < 16; m <<= 1) {
        s1[r] += __shfl_xor(s1[r], m, 16);
        s2[r] += __shfl_xor(s2[r], m, 16);
      }
      const float mu = s1[r] * (1.f / 192.f);
      const float va = s2[r] * (1.f / 192.f) - mu * mu;
      s1[r] = mu; s2[r] = rsqrtf(va + 1e-5f);
    }
#pragma unroll
    for (int nt = 0; nt < 12; ++nt) {
      const int col = nt * 16 + lc;
      const float g = lng[col], be = lnb[col];
#pragma unroll
      for (int r = 0; r < 4; ++r) {
        float v = (acc[nt][r] - s1[r]) * s2[r] * g + be;
        v = v > 0.f ? v : 0.2f * v;
        win[(quad * 4 + r) * AS + col] = v;
      }
    }
  }
  __syncthreads();

  // GEMM2: z = y @ W2^T + b2
  s16x8 ah[6], al[6];
#pragma unroll
  for (int ks = 0; ks < 6; ++ks) split8(&win[lc * AS + ks * 32 + quad * 8], ah[ks], al[ks]);
#pragma unroll
  for (int nt = 0; nt < 12; ++nt) acc[nt] = vzero;
  gemm3p<12, 6>(acc, ah, al, pW2, lane);
#pragma unroll
  for (int nt = 0; nt < 12; ++nt) {
    const int col = nt * 16 + lc;
    const float bb = b2[col];
#pragma unroll
    for (int r = 0; r < 4; ++r) win[(quad * 4 + r) * AS + col] = acc[nt][r] + bb;
  }
  __syncthreads();

  // GEMM3 (fused gates): rz = z @ Wih_a[0:128]^T + h @ Whh_a[0:128]^T; ni/nh separate.
#pragma unroll
  for (int ks = 0; ks < 6; ++ks) split8(&win[lc * AS + ks * 32 + quad * 8], ah[ks], al[ks]);
  f32x4 rz[8], ni[4], nh[4], ro[4];
#pragma unroll
  for (int nt = 0; nt < 8; ++nt) rz[nt] = vzero;
#pragma unroll
  for (int nt = 0; nt < 4; ++nt) { ni[nt] = vzero; nh[nt] = vzero; ro[nt] = vzero; }
  gemm3p<8, 6, 12>(rz, ah, al, pWih, lane);
  gemm3p<4, 6, 12>(ni, ah, al, pWih + 8 * 6 * 512, lane);

  // h-side: gh parts + residual (h = node_feats rows from global)
  s16x8 hh[2], hl[2];
  {
    const int gr = nb0 + w * 16 + lc;
    const float* hp = nf + (size_t)(gr < NN ? gr : NN - 1) * ND;
#pragma unroll
    for (int ks = 0; ks < 2; ++ks) split8(hp + ks * 32 + quad * 8, hh[ks], hl[ks]);
  }
  gemm3p<8, 2, 12>(rz, hh, hl, pWhh, lane);
  gemm3p<4, 2, 12>(nh, hh, hl, pWhh + 8 * 2 * 512, lane);
  gemm3p<4, 2>(ro, hh, hl, pWra, lane);

  // GRU + residual + leaky(0.01) -> update_nodes
#pragma unroll
  for (int nt = 0; nt < 4; ++nt) {
    const int col = nt * 16 + lc;
    const float bir = bih[col], biz = bih[64 + col], bin = bih[128 + col];
    const float bhr = bhh[col], bhz = bhh[64 + col], bhn = bhh[128 + col];
    const float br = bra[col];
#pragma unroll
    for (int r = 0; r < 4; ++r) {
      const int node = nb0 + w * 16 + quad * 4 + r;
      if (node < NN) {
        const float h = nf[(size_t)node * ND + col];
        const float rg = fsigmoid(rz[nt][r] + bir + bhr);
        const float zg = fsigmoid(rz[nt + 4][r] + biz + bhz);
        const float ng = ftanh(ni[nt][r] + bin + rg * (nh[nt][r] + bhn));
        float v = (1.f - zg) * ng + zg * h + ro[nt][r] + br;
        v = v > 0.f ? v : 0.01f * v;
        outn[(size_t)node * ND + col] = v;
      }
    }
  }
}

// ---------- launch ----------
extern "C" void kernel_launch(void* const* d_in, const int* in_sizes, int n_in,
                              void* d_out, int out_size, void* d_ws, size_t ws_size,
                              hipStream_t stream) {
  (void)in_sizes; (void)n_in; (void)out_size; (void)ws_size;
  const float* nf    = (const float*)d_in[0];
  const float* ef    = (const float*)d_in[1];
  const int*   src   = (const int*)d_in[2];
  const int*   dst   = (const int*)d_in[3];
  const float* W1e   = (const float*)d_in[4];
  const float* W1n   = (const float*)d_in[5];
  const float* b1    = (const float*)d_in[6];
  const float* lng   = (const float*)d_in[7];
  const float* lnb   = (const float*)d_in[8];
  const float* W2    = (const float*)d_in[9];
  const float* b2    = (const float*)d_in[10];
  const float* Wih_e = (const float*)d_in[11];
  const float* Whh_e = (const float*)d_in[12];
  const float* bih_e = (const float*)d_in[13];
  const float* bhh_e = (const float*)d_in[14];
  const float* Wih_a = (const float*)d_in[15];
  const float* Whh_a = (const float*)d_in[16];
  const float* bih_a = (const float*)d_in[17];
  const float* bhh_a = (const float*)d_in[18];
  const float* Wre   = (const float*)d_in[19];
  const float* bre   = (const float*)d_in[20];
  const float* Wra   = (const float*)d_in[21];
  const float* bra   = (const float*)d_in[22];

  // workspace layout (bytes)
  unsigned short* packs = (unsigned short*)d_ws;        // 917,504 B
  char* base = (char*)d_ws;
  int* cnt    = (int*)(base + 917504);                  // NN ints
  int* roff   = (int*)(base + 1117504);                 // NN+1 ints
  int* cursor = (int*)(base + 1317512);                 // NN ints
  int* elist  = (int*)(base + 1517512);                 // EE ints (ends at 4,717,512 B)

  constexpr int OFF_W1e = 0, OFF_W1n = 73728, OFF_W2 = 172032, OFF_Wihe = 245760,
                OFF_Whhe = 319488, OFF_Wre = 344064, OFF_Wiha = 352256,
                OFF_Whha = 425984, OFF_Wra = 450560;

  float* out_nodes = (float*)d_out;
  float* out_edges = out_nodes + (size_t)NN * ND;

  k_pack<<<896, 256, 0, stream>>>(W1e, W1n, W2, Wih_e, Whh_e, Wre, Wih_a, Whh_a, Wra, packs);
  k_zero<<<(NN + 255) / 256, 256, 0, stream>>>(cnt);
  k_hist<<<(EE + 255) / 256, 256, 0, stream>>>(dst, cnt);
  k_scan<<<1, 1024, 0, stream>>>(cnt, roff, cursor);
  k_scatter<<<(EE + 255) / 256, 256, 0, stream>>>(dst, cursor, elist);

  edge_kernel<<<EE / 64, 256, 0, stream>>>(
      nf, ef, src, dst, b1, lng, lnb, b2, bih_e, bhh_e, bre,
      packs + OFF_W1e, packs + OFF_W2, packs + OFF_Wihe, packs + OFF_Whhe, packs + OFF_Wre,
      out_edges);

  node_kernel<<<(NN + 63) / 64, 256, 0, stream>>>(
      nf, src, roff, elist, b1, lng, lnb, b2, bih_a, bhh_a, bra,
      packs + OFF_W1n, packs + OFF_W2, packs + OFF_Wiha, packs + OFF_Whha, packs + OFF_Wra,
      out_edges, out_nodes);
}

// Round 2
// 1814.405 us; speedup vs baseline: 1.3196x; 1.1281x over previous
//
#include <hip/hip_runtime.h>

// Problem constants (match reference)
#define NN 50000
#define EE 800000
#define ND 64
#define ED 64
#define HD 192
#define AS 196   // LDS activation row stride in floats (192 + 4; %32==4 -> max 2-way bank aliasing, free)

typedef short s16x8 __attribute__((ext_vector_type(8)));
typedef float f32x4 __attribute__((ext_vector_type(4)));

#define MFMA16 __builtin_amdgcn_mfma_f32_16x16x32_bf16

// ---------- numeric helpers ----------
__device__ __forceinline__ unsigned short bf16rn(float x) {
  unsigned u = __float_as_uint(x);
  return (unsigned short)((u + 0x7fffu + ((u >> 16) & 1u)) >> 16);
}

// Split 8 consecutive fp32 into hi/lo bf16 fragments (fp32-accurate 2-term representation).
__device__ __forceinline__ void split8(const float* p, s16x8& hi, s16x8& lo) {
  f32x4 a = *(const f32x4*)p;
  f32x4 b = *(const f32x4*)(p + 4);
#pragma unroll
  for (int j = 0; j < 4; ++j) {
    unsigned short h = bf16rn(a[j]);
    float hf = __uint_as_float(((unsigned)h) << 16);
    unsigned short l = bf16rn(a[j] - hf);
    hi[j] = (short)h; lo[j] = (short)l;
  }
#pragma unroll
  for (int j = 0; j < 4; ++j) {
    unsigned short h = bf16rn(b[j]);
    float hf = __uint_as_float(((unsigned)h) << 16);
    unsigned short l = bf16rn(b[j] - hf);
    hi[4 + j] = (short)h; lo[4 + j] = (short)l;
  }
}

__device__ __forceinline__ float fsigmoid(float x) { return 1.f / (1.f + __expf(-x)); }
__device__ __forceinline__ float ftanh(float x) {
  const float ax = fabsf(x);
  const float t = __expf(2.f * ax);
  const float r = 1.f - 2.f / (t + 1.f);
  return x >= 0.f ? r : -r;
}

// ---------- GEMM core ----------
// D += A * W^T using split-bf16 (3 MFMAs per k-slab: ah*bh + al*bh + ah*bl).
// A-frag: lane holds A[row = lane&15][k = ks*32 + (lane>>4)*8 + j]
// B pack: pack[((nt*KS+ks)*64 + lane)*8 + j] = W[nt*16 + (lane&15)][ks*32 + (lane>>4)*8 + j]
// hi plane at offset 0, lo plane at offset NTOT*KS*512 (NTOT = full-matrix NT; pass pack +
// nt0*KS*512 to run a sub-slice of N — the relative lo-plane offset stays NTOT*KS*512).
template <int NT, int KS, int NTOT = NT>
__device__ __forceinline__ void gemm3p(f32x4* acc, const s16x8* ah, const s16x8* al,
                                       const unsigned short* __restrict__ pack, int lane) {
  const int HOFF = NTOT * KS * 512;
#pragma unroll
  for (int ks = 0; ks < KS; ++ks) {
#pragma unroll
    for (int nt = 0; nt < NT; ++nt) {
      const unsigned short* bp = pack + ((nt * KS + ks) * 64 + lane) * 8;
      s16x8 bh = *(const s16x8*)bp;
      s16x8 bl = *(const s16x8*)(bp + HOFF);
      acc[nt] = MFMA16(ah[ks], bh, acc[nt], 0, 0, 0);
      acc[nt] = MFMA16(al[ks], bh, acc[nt], 0, 0, 0);
      acc[nt] = MFMA16(ah[ks], bl, acc[nt], 0, 0, 0);
    }
  }
}

// ---------- weight packing ----------
// order: 0 W1e(12,6,192) 1 W1n(12,8,256) 2 W2(12,6,192) 3 Wih_e(12,6,192) 4 Whh_e(12,2,64)
//        5 Wre(4,2,64)   6 Wih_a(12,6,192) 7 Whh_a(12,2,64) 8 Wra(4,2,64)
// R2: the Wih_e / Wih_a slots are OVERWRITTEN afterwards by k_packfuse with the
// algebraically-fused Wih@W2 matrices (same 12x6x192 shape/layout); W2 slot becomes dead.
__global__ void k_pack(const float* __restrict__ w0, const float* __restrict__ w1,
                       const float* __restrict__ w2, const float* __restrict__ w3,
                       const float* __restrict__ w4, const float* __restrict__ w5,
                       const float* __restrict__ w6, const float* __restrict__ w7,
                       const float* __restrict__ w8, unsigned short* __restrict__ packs) {
  int gid = blockIdx.x * 256 + threadIdx.x;
  const float* w; int off, sz, KS, K, local;
  if      (gid <  36864) { w = w0; off = 0;      sz = 36864; KS = 6; K = 192; local = gid; }
  else if (gid <  86016) { w = w1; off = 73728;  sz = 49152; KS = 8; K = 256; local = gid - 36864; }
  else if (gid < 122880) { w = w2; off = 172032; sz = 36864; KS = 6; K = 192; local = gid - 86016; }
  else if (gid < 159744) { w = w3; off = 245760; sz = 36864; KS = 6; K = 192; local = gid - 122880; }
  else if (gid < 172032) { w = w4; off = 319488; sz = 12288; KS = 2; K = 64;  local = gid - 159744; }
  else if (gid < 176128) { w = w5; off = 344064; sz = 4096;  KS = 2; K = 64;  local = gid - 172032; }
  else if (gid < 212992) { w = w6; off = 352256; sz = 36864; KS = 6; K = 192; local = gid - 176128; }
  else if (gid < 225280) { w = w7; off = 425984; sz = 12288; KS = 2; K = 64;  local = gid - 212992; }
  else                   { w = w8; off = 450560; sz = 4096;  KS = 2; K = 64;  local = gid - 225280; }
  int j = local & 7;
  int lane = (local >> 3) & 63;
  int t = local >> 9;
  int ks = t % KS, nt = t / KS;
  int n = nt * 16 + (lane & 15);
  int k = ks * 32 + ((lane >> 4) & 3) * 8 + j;
  float v = w[n * K + k];
  unsigned short h = bf16rn(v);
  float hf = __uint_as_float(((unsigned)h) << 16);
  unsigned short l = bf16rn(v - hf);
  packs[off + local] = h;
  packs[off + sz + local] = l;
}

// ---------- fused-weight packing (R2) ----------
// gi = z @ Wih^T with z = y @ W2^T + b2 and z consumed nowhere else
//   =>  gi = y @ (Wih @ W2)^T + (bih + Wih @ b2).
// This kernel computes Wfuse = Wih @ W2 in fp32 on the fly and packs hi/lo planes
// directly into the Wih_e / Wih_a pack slots (no fp32 staging buffer needed).
__global__ void k_packfuse(const float* __restrict__ W2,
                           const float* __restrict__ WihE, const float* __restrict__ WihA,
                           unsigned short* __restrict__ packs) {
  int gid = blockIdx.x * 256 + threadIdx.x;  // 288 blocks -> 73728 threads
  const float* Wih; int off, local;
  if (gid < 36864) { Wih = WihE; off = 245760; local = gid; }
  else             { Wih = WihA; off = 352256; local = gid - 36864; }
  int j = local & 7;
  int lane = (local >> 3) & 63;
  int t = local >> 9;
  int ks = t % 6, nt = t / 6;
  int n = nt * 16 + (lane & 15);
  int k = ks * 32 + ((lane >> 4) & 3) * 8 + j;
  const float* wr = Wih + n * HD;
  float acc = 0.f;
#pragma unroll 4
  for (int jj = 0; jj < HD; ++jj) acc = fmaf(wr[jj], W2[jj * HD + k], acc);
  unsigned short h = bf16rn(acc);
  float hf = __uint_as_float(((unsigned)h) << 16);
  unsigned short l = bf16rn(acc - hf);
  packs[off + local] = h;
  packs[off + 36864 + local] = l;
}

// Fused biases: bf[0:192] = bih_e + Wih_e@b2 ; bf[192:384] = bih_a + Wih_a@b2.
// Written into the (dead-after-k_scatter) cursor workspace region.
__global__ void k_fusebias(const float* __restrict__ WihE, const float* __restrict__ WihA,
                           const float* __restrict__ b2, const float* __restrict__ bihE,
                           const float* __restrict__ bihA, float* __restrict__ bf) {
  int i = threadIdx.x;  // 384 threads
  const float* Wih = (i < 192) ? WihE : WihA;
  const float* bih = (i < 192) ? bihE : bihA;
  int n = (i < 192) ? i : i - 192;
  float acc = bih[n];
  for (int k = 0; k < HD; ++k) acc = fmaf(Wih[n * HD + k], b2[k], acc);
  bf[i] = acc;
}

// ---------- CSR build ----------
__global__ void k_zero(int* __restrict__ cnt) {
  int i = blockIdx.x * 256 + threadIdx.x;
  if (i < NN) cnt[i] = 0;
}
__global__ void k_hist(const int* __restrict__ dst, int* __restrict__ cnt) {
  int e = blockIdx.x * 256 + threadIdx.x;
  if (e < EE) atomicAdd(&cnt[dst[e]], 1);
}
// R2: shuffle-based scan — 3 barriers per 1024-chunk instead of ~20.
__global__ void k_scan(const int* __restrict__ cnt, int* __restrict__ roff, int* __restrict__ cursor) {
  __shared__ int wsum[16];
  const int tid = threadIdx.x;
  const int lane = tid & 63, wid = tid >> 6;
  int carry = 0;
  for (int c = 0; c < 49; ++c) {
    const int idx = c * 1024 + tid;
    const int v = (idx < NN) ? cnt[idx] : 0;
    int x = v;  // inclusive scan within wave
#pragma unroll
    for (int off = 1; off < 64; off <<= 1) {
      int y = __shfl_up(x, off, 64);
      if (lane >= off) x += y;
    }
    if (lane == 63) wsum[wid] = x;
    __syncthreads();
    if (wid == 0 && lane < 16) {
      int s = wsum[lane];
#pragma unroll
      for (int off = 1; off < 16; off <<= 1) {
        int y = __shfl_up(s, off, 16);
        if (lane >= off) s += y;
      }
      wsum[lane] = s;  // inclusive over wave sums
    }
    __syncthreads();
    const int wbase = (wid == 0) ? 0 : wsum[wid - 1];
    const int excl = carry + wbase + x - v;
    if (idx < NN) { roff[idx] = excl; cursor[idx] = excl; }
    const int total = wsum[15];
    __syncthreads();  // protect wsum before next chunk overwrites
    carry += total;
  }
  if (tid == 0) roff[NN] = carry;
}
__global__ void k_scatter(const int* __restrict__ dst, int* __restrict__ cursor, int* __restrict__ elist) {
  int e = blockIdx.x * 256 + threadIdx.x;
  if (e < EE) {
    int p = atomicAdd(&cursor[dst[e]], 1);
    elist[p] = e;
  }
}

// ---------- edge kernel ----------
// 64 edges / block, 4 waves; wave w owns rows [w*16, w*16+16) at a SINGLE stride (AS) in every
// phase, so wave LDS regions are always disjoint. Barriers between phases are insurance only.
//
// R1: fused GRU r/z-gate accumulators (80 live acc regs) -> 3 blocks/CU.
// R2: W2 folded into Wih (Wfuse = Wih@W2, bias bfz = bih + Wih@b2): GEMM2 phase deleted,
//     744 -> 528 MFMAs/wave, one barrier phase and 6 split8 calls removed.
__global__ __launch_bounds__(256, 3)
void edge_kernel(const float* __restrict__ nf, const float* __restrict__ efg,
                 const int* __restrict__ src, const int* __restrict__ dst,
                 const float* __restrict__ b1, const float* __restrict__ lng,
                 const float* __restrict__ lnb,
                 const float* __restrict__ bfz, const float* __restrict__ bhh,
                 const float* __restrict__ bre,
                 const unsigned short* __restrict__ pW1,
                 const unsigned short* __restrict__ pWih, const unsigned short* __restrict__ pWhh,
                 const unsigned short* __restrict__ pWre,
                 float* __restrict__ oute) {
  __shared__ float act[64 * AS];
  const int tid = threadIdx.x;
  const int e0 = blockIdx.x * 64;

  { // gather msg = [h_src | h_dst | e] into act (wave-local rows)
    const int r = tid >> 2, q = tid & 3;
    const int s = src[e0 + r];
    const int d = dst[e0 + r];
    const f32x4* nf4 = (const f32x4*)nf;
    const f32x4* ef4 = (const f32x4*)efg;
#pragma unroll
    for (int i = 0; i < 4; ++i) {
      const int c4 = q * 4 + i;
      *(f32x4*)&act[r * AS + c4 * 4]       = nf4[s * 16 + c4];
      *(f32x4*)&act[r * AS + 64 + c4 * 4]  = nf4[d * 16 + c4];
      *(f32x4*)&act[r * AS + 128 + c4 * 4] = ef4[(e0 + r) * 16 + c4];
    }
  }
  __syncthreads();

  const int w = tid >> 6, lane = tid & 63;
  const int quad = lane >> 4, lc = lane & 15;
  const int arow = w * 16 + lc;          // A-frag row
  const int obase = w * 16 + quad * 4;   // C/D-layout row base (+reg)
  const f32x4 vzero = {0.f, 0.f, 0.f, 0.f};

  s16x8 ah[6], al[6];
  f32x4 acc[12];

  // GEMM1: y = msg @ W1e^T + b1 -> LayerNorm -> leaky(0.2) -> act
#pragma unroll
  for (int ks = 0; ks < 6; ++ks) split8(&act[arow * AS + ks * 32 + quad * 8], ah[ks], al[ks]);
#pragma unroll
  for (int nt = 0; nt < 12; ++nt) acc[nt] = vzero;
  gemm3p<12, 6>(acc, ah, al, pW1, lane);
  {
    float s1[4] = {0, 0, 0, 0}, s2[4] = {0, 0, 0, 0};
#pragma unroll
    for (int nt = 0; nt < 12; ++nt) {
      const float bb = b1[nt * 16 + lc];
#pragma unroll
      for (int r = 0; r < 4; ++r) {
        const float v = acc[nt][r] + bb;
        acc[nt][r] = v; s1[r] += v; s2[r] += v * v;
      }
    }
#pragma unroll
    for (int r = 0; r < 4; ++r) {
#pragma unroll
      for (int m = 1; m < 16; m <<= 1) {
        s1[r] += __shfl_xor(s1[r], m, 16);
        s2[r] += __shfl_xor(s2[r], m, 16);
      }
      const float mu = s1[r] * (1.f / 192.f);
      const float va = s2[r] * (1.f / 192.f) - mu * mu;
      s1[r] = mu; s2[r] = rsqrtf(va + 1e-5f);
    }
#pragma unroll
    for (int nt = 0; nt < 12; ++nt) {
      const int col = nt * 16 + lc;
      const float g = lng[col], be = lnb[col];
#pragma unroll
      for (int r = 0; r < 4; ++r) {
        float v = (acc[nt][r] - s1[r]) * s2[r] * g + be;
        v = v > 0.f ? v : 0.2f * v;
        act[(obase + r) * AS + col] = v;
      }
    }
  }
  __syncthreads();

  // Fused GEMM (was GEMM2+GEMM3): gi = y @ Wfuse^T ; rz fused with e-side, ni/nh separate.
#pragma unroll
  for (int ks = 0; ks < 6; ++ks) split8(&act[arow * AS + ks * 32 + quad * 8], ah[ks], al[ks]);
  f32x4 rz[8], ni[4], nh[4], ro[4];
#pragma unroll
  for (int nt = 0; nt < 8; ++nt) rz[nt] = vzero;
#pragma unroll
  for (int nt = 0; nt < 4; ++nt) { ni[nt] = vzero; nh[nt] = vzero; ro[nt] = vzero; }
  gemm3p<8, 6, 12>(rz, ah, al, pWih, lane);
  gemm3p<4, 6, 12>(ni, ah, al, pWih + 8 * 6 * 512, lane);

  // e-side: gh parts + residual (A-frags straight from global edge_feats, L2-hot)
  s16x8 eh[2], el[2];
#pragma unroll
  for (int ks = 0; ks < 2; ++ks)
    split8(efg + (size_t)(e0 + arow) * ED + ks * 32 + quad * 8, eh[ks], el[ks]);
  gemm3p<8, 2, 12>(rz, eh, el, pWhh, lane);
  gemm3p<4, 2, 12>(nh, eh, el, pWhh + 8 * 2 * 512, lane);
  gemm3p<4, 2>(ro, eh, el, pWre, lane);

  // GRU + residual + leaky(0.01) -> update_edges (bfz = bih + Wih@b2)
#pragma unroll
  for (int nt = 0; nt < 4; ++nt) {
    const int col = nt * 16 + lc;
    const float bir = bfz[col], biz = bfz[64 + col], bin = bfz[128 + col];
    const float bhr = bhh[col], bhz = bhh[64 + col], bhn = bhh[128 + col];
    const float br = bre[col];
#pragma unroll
    for (int r = 0; r < 4; ++r) {
      const int row = obase + r;
      const float h = efg[(size_t)(e0 + row) * ED + col];
      const float rg = fsigmoid(rz[nt][r] + bir + bhr);
      const float zg = fsigmoid(rz[nt + 4][r] + biz + bhz);
      const float ng = ftanh(ni[nt][r] + bin + rg * (nh[nt][r] + bhn));
      float v = (1.f - zg) * ng + zg * h + ro[nt][r] + br;
      v = v > 0.f ? v : 0.01f * v;
      oute[(size_t)(e0 + row) * ED + col] = v;
    }
  }
}

// ---------- node kernel ----------
// 64 nodes / block, 4 waves. Every wave works inside its own 4096-float LDS window
// (act + w*4096) across ALL phases, so the stride-256 agg layout and stride-AS activation
// layout can never overlap another wave's region. LDS 64KB caps residency at 2 blocks/CU.
// R2: same W2->Wih fusion as edge kernel (GEMM2 deleted, 816 -> 600 MFMAs/wave).
__global__ __launch_bounds__(256, 2)
void node_kernel(const float* __restrict__ nf,
                 const int* __restrict__ src,
                 const int* __restrict__ roff, const int* __restrict__ elist,
                 const float* __restrict__ b1, const float* __restrict__ lng,
                 const float* __restrict__ lnb,
                 const float* __restrict__ bfz, const float* __restrict__ bhh,
                 const float* __restrict__ bra,
                 const unsigned short* __restrict__ pW1,
                 const unsigned short* __restrict__ pWih, const unsigned short* __restrict__ pWhh,
                 const unsigned short* __restrict__ pWra,
                 const float* __restrict__ upd,
                 float* __restrict__ outn) {
  __shared__ float act[4 * 4096];  // 64 KB; one 4096-float window per wave
  const int tid = threadIdx.x;
  const int w = tid >> 6, lane = tid & 63;
  const int nb0 = blockIdx.x * 64;
  float* win = act + w * 4096;

  { // aggregation: window row i (node nb0 + w*16 + i) = [sum(128) | max(128)] at stride 256
    const int half = lane >> 5, c2 = (lane & 31) * 2;
#pragma unroll 1
    for (int i = 0; i < 16; ++i) {
      const int node = nb0 + w * 16 + i;
      float s0 = 0.f, s1v = 0.f;
      float m0 = -__builtin_inff(), m1 = -__builtin_inff();
      if (node < NN) {
        const int sidx = roff[node], eidx = roff[node + 1];
        int ix = sidx;
        for (; ix + 1 < eidx; ix += 2) {
          const int ea = elist[ix], eb = elist[ix + 1];
          const float* pa = half ? (upd + (size_t)ea * ED + c2) : (nf + (size_t)src[ea] * ND + c2);
          const float* pb = half ? (upd + (size_t)eb * ED + c2) : (nf + (size_t)src[eb] * ND + c2);
          const float a0 = pa[0], a1 = pa[1], c0 = pb[0], c1 = pb[1];
          s0 += a0 + c0; s1v += a1 + c1;
          m0 = fmaxf(m0, fmaxf(a0, c0)); m1 = fmaxf(m1, fmaxf(a1, c1));
        }
        if (ix < eidx) {
          const int ea = elist[ix];
          const float* pa = half ? (upd + (size_t)ea * ED + c2) : (nf + (size_t)src[ea] * ND + c2);
          const float a0 = pa[0], a1 = pa[1];
          s0 += a0; s1v += a1;
          m0 = fmaxf(m0, a0); m1 = fmaxf(m1, a1);
        }
        if (sidx == eidx) { m0 = 0.f; m1 = 0.f; }  // empty mailbox -> 0
      } else {
        m0 = 0.f; m1 = 0.f;  // tail rows: zero-fill (sum already 0)
      }
      const int cs = half * 64 + c2;
      win[i * 256 + cs] = s0;
      win[i * 256 + cs + 1] = s1v;
      win[i * 256 + 128 + cs] = m0;
      win[i * 256 + 128 + cs + 1] = m1;
    }
  }
  __syncthreads();

  const int quad = lane >> 4, lc = lane & 15;
  const f32x4 vzero = {0.f, 0.f, 0.f, 0.f};

  // GEMM1: y = agg(K=256) @ W1n^T + b1 -> LN -> leaky(0.2) -> window @ stride AS
  s16x8 ah8[8], al8[8];
#pragma unroll
  for (int ks = 0; ks < 8; ++ks) split8(&win[lc * 256 + ks * 32 + quad * 8], ah8[ks], al8[ks]);
  f32x4 acc[12];
#pragma unroll
  for (int nt = 0; nt < 12; ++nt) acc[nt] = vzero;
  gemm3p<12, 8>(acc, ah8, al8, pW1, lane);
  {
    float s1[4] = {0, 0, 0, 0}, s2[4] = {0, 0, 0, 0};
#pragma unroll
    for (int nt = 0; nt < 12; ++nt) {
      const float bb = b1[nt * 16 + lc];
#pragma unroll
      for (int r = 0; r < 4; ++r) {
        const float v = acc[nt][r] + bb;
        acc[nt][r] = v; s1[r] += v; s2[r] += v * v;
      }
    }
#pragma unroll
    for (int r = 0; r < 4; ++r) {
#pragma unroll
      for (int m = 1; m < 16; m <<= 1) {
        s1[r] += __shfl_xor(s1[r], m, 16);
        s2[r] += __shfl_xor(s2[r], m, 16);
      }
      const float mu = s1[r] * (1.f / 192.f);
      const float va = s2[r] * (1.f / 192.f) - mu * mu;
      s1[r] = mu; s2[r] = rsqrtf(va + 1e-5f);
    }
#pragma unroll
    for (int nt = 0; nt < 12; ++nt) {
      const int col = nt * 16 + lc;
      const float g = lng[col], be = lnb[col];
#pragma unroll
      for (int r = 0; r < 4; ++r) {
        float v = (acc[nt][r] - s1[r]) * s2[r] * g + be;
        v = v > 0.f ? v : 0.2f * v;
        win[(quad * 4 + r) * AS + col] = v;
      }
    }
  }
  __syncthreads();

  // Fused GEMM (was GEMM2+GEMM3): gi = y @ Wfuse_a^T ; rz fused with h-side, ni/nh separate.
  s16x8 ah[6], al[6];
#pragma unroll
  for (int ks = 0; ks < 6; ++ks) split8(&win[lc * AS + ks * 32 + quad * 8], ah[ks], al[ks]);
  f32x4 rz[8], ni[4], nh[4], ro[4];
#pragma unroll
  for (int nt = 0; nt < 8; ++nt) rz[nt] = vzero;
#pragma unroll
  for (int nt = 0; nt < 4; ++nt) { ni[nt] = vzero; nh[nt] = vzero; ro[nt] = vzero; }
  gemm3p<8, 6, 12>(rz, ah, al, pWih, lane);
  gemm3p<4, 6, 12>(ni, ah, al, pWih + 8 * 6 * 512, lane);

  // h-side: gh parts + residual (h = node_feats rows from global)
  s16x8 hh[2], hl[2];
  {
    const int gr = nb0 + w * 16 + lc;
    const float* hp = nf + (size_t)(gr < NN ? gr : NN - 1) * ND;
#pragma unroll
    for (int ks = 0; ks < 2; ++ks) split8(hp + ks * 32 + quad * 8, hh[ks], hl[ks]);
  }
  gemm3p<8, 2, 12>(rz, hh, hl, pWhh, lane);
  gemm3p<4, 2, 12>(nh, hh, hl, pWhh + 8 * 2 * 512, lane);
  gemm3p<4, 2>(ro, hh, hl, pWra, lane);

  // GRU + residual + leaky(0.01) -> update_nodes (bfz = bih + Wih@b2)
#pragma unroll
  for (int nt = 0; nt < 4; ++nt) {
    const int col = nt * 16 + lc;
    const float bir = bfz[col], biz = bfz[64 + col], bin = bfz[128 + col];
    const float bhr = bhh[col], bhz = bhh[64 + col], bhn = bhh[128 + col];
    const float br = bra[col];
#pragma unroll
    for (int r = 0; r < 4; ++r) {
      const int node = nb0 + w * 16 + quad * 4 + r;
      if (node < NN) {
        const float h = nf[(size_t)node * ND + col];
        const float rg = fsigmoid(rz[nt][r] + bir + bhr);
        const float zg = fsigmoid(rz[nt + 4][r] + biz + bhz);
        const float ng = ftanh(ni[nt][r] + bin + rg * (nh[nt][r] + bhn));
        float v = (1.f - zg) * ng + zg * h + ro[nt][r] + br;
        v = v > 0.f ? v : 0.01f * v;
        outn[(size_t)node * ND + col] = v;
      }
    }
  }
}

// ---------- launch ----------
extern "C" void kernel_launch(void* const* d_in, const int* in_sizes, int n_in,
                              void* d_out, int out_size, void* d_ws, size_t ws_size,
                              hipStream_t stream) {
  (void)in_sizes; (void)n_in; (void)out_size; (void)ws_size;
  const float* nf    = (const float*)d_in[0];
  const float* ef    = (const float*)d_in[1];
  const int*   src   = (const int*)d_in[2];
  const int*   dst   = (const int*)d_in[3];
  const float* W1e   = (const float*)d_in[4];
  const float* W1n   = (const float*)d_in[5];
  const float* b1    = (const float*)d_in[6];
  const float* lng   = (const float*)d_in[7];
  const float* lnb   = (const float*)d_in[8];
  const float* W2    = (const float*)d_in[9];
  const float* b2    = (const float*)d_in[10];
  const float* Wih_e = (const float*)d_in[11];
  const float* Whh_e = (const float*)d_in[12];
  const float* bih_e = (const float*)d_in[13];
  const float* bhh_e = (const float*)d_in[14];
  const float* Wih_a = (const float*)d_in[15];
  const float* Whh_a = (const float*)d_in[16];
  const float* bih_a = (const float*)d_in[17];
  const float* bhh_a = (const float*)d_in[18];
  const float* Wre   = (const float*)d_in[19];
  const float* bre   = (const float*)d_in[20];
  const float* Wra   = (const float*)d_in[21];
  const float* bra   = (const float*)d_in[22];

  // workspace layout (bytes)
  unsigned short* packs = (unsigned short*)d_ws;        // 917,504 B
  char* base = (char*)d_ws;
  int* cnt    = (int*)(base + 917504);                  // NN ints
  int* roff   = (int*)(base + 1117504);                 // NN+1 ints
  int* cursor = (int*)(base + 1317512);                 // NN ints (dead after k_scatter ->
                                                        //   reused for fused biases bf[384])
  int* elist  = (int*)(base + 1517512);                 // EE ints (ends at 4,717,512 B)
  float* bfused = (float*)cursor;                       // bf[0:192]=edge, bf[192:384]=node

  constexpr int OFF_W1e = 0, OFF_W1n = 73728,
                OFF_Wihe = 245760, OFF_Whhe = 319488, OFF_Wre = 344064,
                OFF_Wiha = 352256, OFF_Whha = 425984, OFF_Wra = 450560;

  float* out_nodes = (float*)d_out;
  float* out_edges = out_nodes + (size_t)NN * ND;

  k_pack<<<896, 256, 0, stream>>>(W1e, W1n, W2, Wih_e, Whh_e, Wre, Wih_a, Whh_a, Wra, packs);
  k_packfuse<<<288, 256, 0, stream>>>(W2, Wih_e, Wih_a, packs);  // overwrites Wihe/Wiha slots
  k_zero<<<(NN + 255) / 256, 256, 0, stream>>>(cnt);
  k_hist<<<(EE + 255) / 256, 256, 0, stream>>>(dst, cnt);
  k_scan<<<1, 1024, 0, stream>>>(cnt, roff, cursor);
  k_scatter<<<(EE + 255) / 256, 256, 0, stream>>>(dst, cursor, elist);
  k_fusebias<<<1, 384, 0, stream>>>(Wih_e, Wih_a, b2, bih_e, bih_a, bfused);  // cursor now dead

  edge_kernel<<<EE / 64, 256, 0, stream>>>(
      nf, ef, src, dst, b1, lng, lnb, bfused, bhh_e, bre,
      packs + OFF_W1e, packs + OFF_Wihe, packs + OFF_Whhe, packs + OFF_Wre,
      out_edges);

  node_kernel<<<(NN + 63) / 64, 256, 0, stream>>>(
      nf, src, roff, elist, b1, lng, lnb, bfused + 192, bhh_a, bra,
      packs + OFF_W1n, packs + OFF_Wiha, packs + OFF_Whha, packs + OFF_Wra,
      out_edges, out_nodes);
}

// Round 3
// 1489.079 us; speedup vs baseline: 1.6079x; 1.2185x over previous
//
#include <hip/hip_runtime.h>

// Problem constants (match reference)
#define NN 50000
#define EE 800000
#define ND 64
#define ED 64
#define HD 192
#define AS 196   // LDS activation row stride (elements); %32==4 -> balanced bank usage

typedef short s16x8 __attribute__((ext_vector_type(8)));
typedef float f32x4 __attribute__((ext_vector_type(4)));
typedef unsigned u32x4 __attribute__((ext_vector_type(4)));

#define MFMA16 __builtin_amdgcn_mfma_f32_16x16x32_bf16

// ---------- numeric helpers ----------
__device__ __forceinline__ unsigned short bf16rn(float x) {
  unsigned u = __float_as_uint(x);
  return (unsigned short)((u + 0x7fffu + ((u >> 16) & 1u)) >> 16);
}

// fp32 -> packed (hi bf16 << 16) | (lo bf16 of remainder). Same hi/lo pair split8 produced.
__device__ __forceinline__ unsigned packhl(float x) {
  unsigned short h = bf16rn(x);
  float hf = __uint_as_float(((unsigned)h) << 16);
  unsigned short l = bf16rn(x - hf);
  return (((unsigned)h) << 16) | l;
}

// 8 packed u32 (LDS) -> hi/lo s16x8 fragments via v_perm (1 op per output pair per plane).
__device__ __forceinline__ void unpack8(const unsigned* p, s16x8& hi, s16x8& lo) {
  u32x4 a = *(const u32x4*)p;
  u32x4 b = *(const u32x4*)(p + 4);
  u32x4 h, l;
  h[0] = __builtin_amdgcn_perm(a[1], a[0], 0x07060302u);
  h[1] = __builtin_amdgcn_perm(a[3], a[2], 0x07060302u);
  h[2] = __builtin_amdgcn_perm(b[1], b[0], 0x07060302u);
  h[3] = __builtin_amdgcn_perm(b[3], b[2], 0x07060302u);
  l[0] = __builtin_amdgcn_perm(a[1], a[0], 0x05040100u);
  l[1] = __builtin_amdgcn_perm(a[3], a[2], 0x05040100u);
  l[2] = __builtin_amdgcn_perm(b[1], b[0], 0x05040100u);
  l[3] = __builtin_amdgcn_perm(b[3], b[2], 0x05040100u);
  hi = __builtin_bit_cast(s16x8, h);
  lo = __builtin_bit_cast(s16x8, l);
}

// Split 8 consecutive fp32 into hi/lo bf16 fragments (fp32-accurate 2-term representation).
__device__ __forceinline__ void split8(const float* p, s16x8& hi, s16x8& lo) {
  f32x4 a = *(const f32x4*)p;
  f32x4 b = *(const f32x4*)(p + 4);
#pragma unroll
  for (int j = 0; j < 4; ++j) {
    unsigned short h = bf16rn(a[j]);
    float hf = __uint_as_float(((unsigned)h) << 16);
    unsigned short l = bf16rn(a[j] - hf);
    hi[j] = (short)h; lo[j] = (short)l;
  }
#pragma unroll
  for (int j = 0; j < 4; ++j) {
    unsigned short h = bf16rn(b[j]);
    float hf = __uint_as_float(((unsigned)h) << 16);
    unsigned short l = bf16rn(b[j] - hf);
    hi[4 + j] = (short)h; lo[4 + j] = (short)l;
  }
}

__device__ __forceinline__ float fsigmoid(float x) { return 1.f / (1.f + __expf(-x)); }
__device__ __forceinline__ float ftanh(float x) {
  const float ax = fabsf(x);
  const float t = __expf(2.f * ax);
  const float r = 1.f - 2.f / (t + 1.f);
  return x >= 0.f ? r : -r;
}

// MFMA triple: fp32-accurate product via ah*bh + al*bh + ah*bl.
#define TRI(ACC, AH, AL, BH, BL)          \
  ACC = MFMA16(AH, BH, ACC, 0, 0, 0);     \
  ACC = MFMA16(AL, BH, ACC, 0, 0, 0);     \
  ACC = MFMA16(AH, BL, ACC, 0, 0, 0);

// ---------- GEMM core (M-split form, used by node kernel) ----------
template <int NT, int KS, int NTOT = NT>
__device__ __forceinline__ void gemm3p(f32x4* acc, const s16x8* ah, const s16x8* al,
                                       const unsigned short* __restrict__ pack, int lane) {
  const int HOFF = NTOT * KS * 512;
#pragma unroll
  for (int ks = 0; ks < KS; ++ks) {
#pragma unroll
    for (int nt = 0; nt < NT; ++nt) {
      const unsigned short* bp = pack + ((nt * KS + ks) * 64 + lane) * 8;
      s16x8 bh = *(const s16x8*)bp;
      s16x8 bl = *(const s16x8*)(bp + HOFF);
      TRI(acc[nt], ah[ks], al[ks], bh, bl);
    }
  }
}

// ---------- weight packing ----------
// order: 0 W1e(12,6,192) 1 W1n(12,8,256) 2 W2(12,6,192) 3 Wih_e(12,6,192) 4 Whh_e(12,2,64)
//        5 Wre(4,2,64)   6 Wih_a(12,6,192) 7 Whh_a(12,2,64) 8 Wra(4,2,64)
// Wih_e / Wih_a slots are OVERWRITTEN by k_packfuse with fused Wih@W2 (same layout).
__global__ void k_pack(const float* __restrict__ w0, const float* __restrict__ w1,
                       const float* __restrict__ w2, const float* __restrict__ w3,
                       const float* __restrict__ w4, const float* __restrict__ w5,
                       const float* __restrict__ w6, const float* __restrict__ w7,
                       const float* __restrict__ w8, unsigned short* __restrict__ packs) {
  int gid = blockIdx.x * 256 + threadIdx.x;
  const float* w; int off, sz, KS, K, local;
  if      (gid <  36864) { w = w0; off = 0;      sz = 36864; KS = 6; K = 192; local = gid; }
  else if (gid <  86016) { w = w1; off = 73728;  sz = 49152; KS = 8; K = 256; local = gid - 36864; }
  else if (gid < 122880) { w = w2; off = 172032; sz = 36864; KS = 6; K = 192; local = gid - 86016; }
  else if (gid < 159744) { w = w3; off = 245760; sz = 36864; KS = 6; K = 192; local = gid - 122880; }
  else if (gid < 172032) { w = w4; off = 319488; sz = 12288; KS = 2; K = 64;  local = gid - 159744; }
  else if (gid < 176128) { w = w5; off = 344064; sz = 4096;  KS = 2; K = 64;  local = gid - 172032; }
  else if (gid < 212992) { w = w6; off = 352256; sz = 36864; KS = 6; K = 192; local = gid - 176128; }
  else if (gid < 225280) { w = w7; off = 425984; sz = 12288; KS = 2; K = 64;  local = gid - 212992; }
  else                   { w = w8; off = 450560; sz = 4096;  KS = 2; K = 64;  local = gid - 225280; }
  int j = local & 7;
  int lane = (local >> 3) & 63;
  int t = local >> 9;
  int ks = t % KS, nt = t / KS;
  int n = nt * 16 + (lane & 15);
  int k = ks * 32 + ((lane >> 4) & 3) * 8 + j;
  float v = w[n * K + k];
  unsigned short h = bf16rn(v);
  float hf = __uint_as_float(((unsigned)h) << 16);
  unsigned short l = bf16rn(v - hf);
  packs[off + local] = h;
  packs[off + sz + local] = l;
}

// ---------- fused-weight packing ----------
__global__ void k_packfuse(const float* __restrict__ W2,
                           const float* __restrict__ WihE, const float* __restrict__ WihA,
                           unsigned short* __restrict__ packs) {
  int gid = blockIdx.x * 256 + threadIdx.x;  // 288 blocks -> 73728 threads
  const float* Wih; int off, local;
  if (gid < 36864) { Wih = WihE; off = 245760; local = gid; }
  else             { Wih = WihA; off = 352256; local = gid - 36864; }
  int j = local & 7;
  int lane = (local >> 3) & 63;
  int t = local >> 9;
  int ks = t % 6, nt = t / 6;
  int n = nt * 16 + (lane & 15);
  int k = ks * 32 + ((lane >> 4) & 3) * 8 + j;
  const float* wr = Wih + n * HD;
  float acc = 0.f;
#pragma unroll 4
  for (int jj = 0; jj < HD; ++jj) acc = fmaf(wr[jj], W2[jj * HD + k], acc);
  unsigned short h = bf16rn(acc);
  float hf = __uint_as_float(((unsigned)h) << 16);
  unsigned short l = bf16rn(acc - hf);
  packs[off + local] = h;
  packs[off + 36864 + local] = l;
}

__global__ void k_fusebias(const float* __restrict__ WihE, const float* __restrict__ WihA,
                           const float* __restrict__ b2, const float* __restrict__ bihE,
                           const float* __restrict__ bihA, float* __restrict__ bf) {
  int i = threadIdx.x;  // 384 threads
  const float* Wih = (i < 192) ? WihE : WihA;
  const float* bih = (i < 192) ? bihE : bihA;
  int n = (i < 192) ? i : i - 192;
  float acc = bih[n];
  for (int k = 0; k < HD; ++k) acc = fmaf(Wih[n * HD + k], b2[k], acc);
  bf[i] = acc;
}

// ---------- CSR build ----------
__global__ void k_zero(int* __restrict__ cnt) {
  int i = blockIdx.x * 256 + threadIdx.x;
  if (i < NN) cnt[i] = 0;
}
__global__ void k_hist(const int* __restrict__ dst, int* __restrict__ cnt) {
  int e = blockIdx.x * 256 + threadIdx.x;
  if (e < EE) atomicAdd(&cnt[dst[e]], 1);
}
__global__ void k_scan(const int* __restrict__ cnt, int* __restrict__ roff, int* __restrict__ cursor) {
  __shared__ int wsum[16];
  const int tid = threadIdx.x;
  const int lane = tid & 63, wid = tid >> 6;
  int carry = 0;
  for (int c = 0; c < 49; ++c) {
    const int idx = c * 1024 + tid;
    const int v = (idx < NN) ? cnt[idx] : 0;
    int x = v;  // inclusive scan within wave
#pragma unroll
    for (int off = 1; off < 64; off <<= 1) {
      int y = __shfl_up(x, off, 64);
      if (lane >= off) x += y;
    }
    if (lane == 63) wsum[wid] = x;
    __syncthreads();
    if (wid == 0 && lane < 16) {
      int s = wsum[lane];
#pragma unroll
      for (int off = 1; off < 16; off <<= 1) {
        int y = __shfl_up(s, off, 16);
        if (lane >= off) s += y;
      }
      wsum[lane] = s;
    }
    __syncthreads();
    const int wbase = (wid == 0) ? 0 : wsum[wid - 1];
    const int excl = carry + wbase + x - v;
    if (idx < NN) { roff[idx] = excl; cursor[idx] = excl; }
    const int total = wsum[15];
    __syncthreads();
    carry += total;
  }
  if (tid == 0) roff[NN] = carry;
}
__global__ void k_scatter(const int* __restrict__ dst, int* __restrict__ cursor, int* __restrict__ elist) {
  int e = blockIdx.x * 256 + threadIdx.x;
  if (e < EE) {
    int p = atomicAdd(&cursor[dst[e]], 1);
    elist[p] = e;
  }
}

// ---------- edge kernel (R3: N-split) ----------
// 64 edges / block, 4 waves. Wave w processes ALL 64 rows (4 row-groups) but only N-tiles
// {w, w+4, w+8} -> B-fragments loaded ONCE per block (88 loads/wave vs 352), gate-aligned
// GRU epilogue. Activations live in LDS as packed (hi|lo) bf16 u32 (written once, read by
// all 4 waves via v_perm unpack — bitwise-identical fragments to the old split8 path).
// LN needs cross-wave row sums -> lnPart/lnFin exchange (2 extra barriers).
// Barrier/race plan: msg reads all complete before barrier A (partials written);
// y overwrites msg only after barrier B; fused GEMM reads y after barrier C.
__global__ __launch_bounds__(256, 3)
void edge_kernel(const float* __restrict__ nf, const float* __restrict__ efg,
                 const int* __restrict__ src, const int* __restrict__ dst,
                 const float* __restrict__ b1, const float* __restrict__ lng,
                 const float* __restrict__ lnb,
                 const float* __restrict__ bfz, const float* __restrict__ bhh,
                 const float* __restrict__ bre,
                 const unsigned short* __restrict__ pW1,
                 const unsigned short* __restrict__ pWih, const unsigned short* __restrict__ pWhh,
                 const unsigned short* __restrict__ pWre,
                 float* __restrict__ oute) {
  __shared__ unsigned actP[64 * AS];     // 50176 B packed hi|lo activations
  __shared__ float lnPart[4 * 64 * 2];   // per-wave partial (s1,s2) per row
  __shared__ float lnFin[64 * 2];        // final (mu, rsig) per row
  const int tid = threadIdx.x;
  const int e0 = blockIdx.x * 64;

  { // gather msg = [h_src | h_dst | e] packed hi|lo into actP
    const int r = tid >> 2, q = tid & 3;
    const int s = src[e0 + r];
    const int d = dst[e0 + r];
    const f32x4* nf4 = (const f32x4*)nf;
    const f32x4* ef4 = (const f32x4*)efg;
#pragma unroll
    for (int i = 0; i < 4; ++i) {
      const int c4 = q * 4 + i;
      f32x4 a = nf4[s * 16 + c4];
      f32x4 b = nf4[d * 16 + c4];
      f32x4 c = ef4[(e0 + r) * 16 + c4];
      u32x4 pa, pb, pc;
#pragma unroll
      for (int j = 0; j < 4; ++j) {
        pa[j] = packhl(a[j]); pb[j] = packhl(b[j]); pc[j] = packhl(c[j]);
      }
      *(u32x4*)&actP[r * AS + c4 * 4]       = pa;
      *(u32x4*)&actP[r * AS + 64 + c4 * 4]  = pb;
      *(u32x4*)&actP[r * AS + 128 + c4 * 4] = pc;
    }
  }
  __syncthreads();

  const int w = tid >> 6, lane = tid & 63;
  const int quad = lane >> 4, lc = lane & 15;
  const f32x4 vzero = {0.f, 0.f, 0.f, 0.f};

  // GEMM1: y = msg @ W1e^T ; wave w owns nt in {w, w+4, w+8}, all 4 row-groups.
  f32x4 acc[3][4];
#pragma unroll
  for (int s = 0; s < 3; ++s)
#pragma unroll
    for (int g = 0; g < 4; ++g) acc[s][g] = vzero;
#pragma unroll
  for (int ks = 0; ks < 6; ++ks) {
    s16x8 ah4[4], al4[4];
#pragma unroll
    for (int g = 0; g < 4; ++g)
      unpack8(&actP[(g * 16 + lc) * AS + ks * 32 + quad * 8], ah4[g], al4[g]);
#pragma unroll
    for (int s = 0; s < 3; ++s) {
      const unsigned short* bp = pW1 + (((w + s * 4) * 6 + ks) * 64 + lane) * 8;
      s16x8 bh = *(const s16x8*)bp;
      s16x8 bl = *(const s16x8*)(bp + 36864);
#pragma unroll
      for (int g = 0; g < 4; ++g) { TRI(acc[s][g], ah4[g], al4[g], bh, bl); }
    }
  }

  { // bias + per-wave partial LN sums (over this wave's 48 cols)
    float p1[16], p2[16];
#pragma unroll
    for (int i = 0; i < 16; ++i) { p1[i] = 0.f; p2[i] = 0.f; }
#pragma unroll
    for (int s = 0; s < 3; ++s) {
      const float bb = b1[(w + s * 4) * 16 + lc];
#pragma unroll
      for (int g = 0; g < 4; ++g)
#pragma unroll
        for (int r = 0; r < 4; ++r) {
          const float v = acc[s][g][r] + bb;
          acc[s][g][r] = v;
          p1[g * 4 + r] += v; p2[g * 4 + r] += v * v;
        }
    }
#pragma unroll
    for (int i = 0; i < 16; ++i) {
#pragma unroll
      for (int m = 1; m < 16; m <<= 1) {
        p1[i] += __shfl_xor(p1[i], m, 16);
        p2[i] += __shfl_xor(p2[i], m, 16);
      }
    }
    if (lc == 0) {
#pragma unroll
      for (int g = 0; g < 4; ++g)
#pragma unroll
        for (int r = 0; r < 4; ++r) {
          const int row = g * 16 + quad * 4 + r;
          lnPart[(w * 64 + row) * 2]     = p1[g * 4 + r];
          lnPart[(w * 64 + row) * 2 + 1] = p2[g * 4 + r];
        }
    }
  }
  __syncthreads();  // A: partials visible; all msg reads complete

  if (lane < 16) {  // finalize LN stats: wave w handles rows [w*16, w*16+16)
    const int row = w * 16 + lane;
    float s1 = 0.f, s2 = 0.f;
#pragma unroll
    for (int wv = 0; wv < 4; ++wv) {
      s1 += lnPart[(wv * 64 + row) * 2];
      s2 += lnPart[(wv * 64 + row) * 2 + 1];
    }
    const float mu = s1 * (1.f / 192.f);
    const float va = s2 * (1.f / 192.f) - mu * mu;
    lnFin[row * 2] = mu;
    lnFin[row * 2 + 1] = rsqrtf(va + 1e-5f);
  }
  __syncthreads();  // B: finals visible; safe to overwrite msg with y

  { // apply LN + leaky(0.2), pack hi|lo, write y in place (wave w writes its 3 col-slices)
    float gg[3], be[3];
#pragma unroll
    for (int s = 0; s < 3; ++s) {
      const int col = (w + s * 4) * 16 + lc;
      gg[s] = lng[col]; be[s] = lnb[col];
    }
#pragma unroll
    for (int g = 0; g < 4; ++g)
#pragma unroll
      for (int r = 0; r < 4; ++r) {
        const int row = g * 16 + quad * 4 + r;
        const float mu = lnFin[row * 2], rsig = lnFin[row * 2 + 1];
#pragma unroll
        for (int s = 0; s < 3; ++s) {
          float v = (acc[s][g][r] - mu) * rsig * gg[s] + be[s];
          v = v > 0.f ? v : 0.2f * v;
          actP[row * AS + (w + s * 4) * 16 + lc] = packhl(v);
        }
      }
  }
  __syncthreads();  // C: y complete

  // Fused GEMM: gi = y @ Wfuse^T. Slots: r-gate nt=w (->rza[0]), z-gate nt=w+4 (->rza[1],
  // gh r/z accumulate into same accs), n-gate nt=w+8 (->ni4; gh n-part separate in nh4).
  f32x4 rza[2][4], ni4[4], nh4[4], ro4[4];
#pragma unroll
  for (int g = 0; g < 4; ++g) {
    rza[0][g] = vzero; rza[1][g] = vzero; ni4[g] = vzero; nh4[g] = vzero; ro4[g] = vzero;
  }
#pragma unroll
  for (int ks = 0; ks < 6; ++ks) {
    s16x8 ah4[4], al4[4];
#pragma unroll
    for (int g = 0; g < 4; ++g)
      unpack8(&actP[(g * 16 + lc) * AS + ks * 32 + quad * 8], ah4[g], al4[g]);
#pragma unroll
    for (int s = 0; s < 3; ++s) {
      const unsigned short* bp = pWih + (((w + s * 4) * 6 + ks) * 64 + lane) * 8;
      s16x8 bh = *(const s16x8*)bp;
      s16x8 bl = *(const s16x8*)(bp + 36864);
      f32x4* dst_acc = (s == 0) ? &rza[0][0] : (s == 1) ? &rza[1][0] : &ni4[0];
#pragma unroll
      for (int g = 0; g < 4; ++g) { TRI(dst_acc[g], ah4[g], al4[g], bh, bl); }
    }
  }

  // e-side: gh = e @ Whh^T (r/z into rza, n into nh4), ro = e @ Wre^T
#pragma unroll
  for (int ks = 0; ks < 2; ++ks) {
    s16x8 eh4[4], el4[4];
#pragma unroll
    for (int g = 0; g < 4; ++g)
      split8(efg + (size_t)(e0 + g * 16 + lc) * ED + ks * 32 + quad * 8, eh4[g], el4[g]);
#pragma unroll
    for (int s = 0; s < 3; ++s) {
      const unsigned short* bp = pWhh + (((w + s * 4) * 2 + ks) * 64 + lane) * 8;
      s16x8 bh = *(const s16x8*)bp;
      s16x8 bl = *(const s16x8*)(bp + 12288);
      f32x4* dst_acc = (s == 0) ? &rza[0][0] : (s == 1) ? &rza[1][0] : &nh4[0];
#pragma unroll
      for (int g = 0; g < 4; ++g) { TRI(dst_acc[g], eh4[g], el4[g], bh, bl); }
    }
    {
      const unsigned short* bp = pWre + ((w * 2 + ks) * 64 + lane) * 8;
      s16x8 bh = *(const s16x8*)bp;
      s16x8 bl = *(const s16x8*)(bp + 4096);
#pragma unroll
      for (int g = 0; g < 4; ++g) { TRI(ro4[g], eh4[g], el4[g], bh, bl); }
    }
  }

  // GRU + residual + leaky(0.01). Wave w owns cols [w*16, w*16+16) for all 64 rows.
  {
    const int col = w * 16 + lc;
    const float bir = bfz[col], biz = bfz[64 + col], bin = bfz[128 + col];
    const float bhr = bhh[col], bhz = bhh[64 + col], bhn = bhh[128 + col];
    const float br = bre[col];
#pragma unroll
    for (int g = 0; g < 4; ++g)
#pragma unroll
      for (int r = 0; r < 4; ++r) {
        const int row = g * 16 + quad * 4 + r;
        const float h = efg[(size_t)(e0 + row) * ED + col];
        const float rgate = fsigmoid(rza[0][g][r] + bir + bhr);
        const float zgate = fsigmoid(rza[1][g][r] + biz + bhz);
        const float ngate = ftanh(ni4[g][r] + bin + rgate * (nh4[g][r] + bhn));
        float v = (1.f - zgate) * ngate + zgate * h + ro4[g][r] + br;
        v = v > 0.f ? v : 0.01f * v;
        oute[(size_t)(e0 + row) * ED + col] = v;
      }
  }
}

// ---------- node kernel (unchanged from R2) ----------
__global__ __launch_bounds__(256, 2)
void node_kernel(const float* __restrict__ nf,
                 const int* __restrict__ src,
                 const int* __restrict__ roff, const int* __restrict__ elist,
                 const float* __restrict__ b1, const float* __restrict__ lng,
                 const float* __restrict__ lnb,
                 const float* __restrict__ bfz, const float* __restrict__ bhh,
                 const float* __restrict__ bra,
                 const unsigned short* __restrict__ pW1,
                 const unsigned short* __restrict__ pWih, const unsigned short* __restrict__ pWhh,
                 const unsigned short* __restrict__ pWra,
                 const float* __restrict__ upd,
                 float* __restrict__ outn) {
  __shared__ float act[4 * 4096];  // 64 KB; one 4096-float window per wave
  const int tid = threadIdx.x;
  const int w = tid >> 6, lane = tid & 63;
  const int nb0 = blockIdx.x * 64;
  float* win = act + w * 4096;

  { // aggregation: window row i = [sum(128) | max(128)] at stride 256
    const int half = lane >> 5, c2 = (lane & 31) * 2;
#pragma unroll 1
    for (int i = 0; i < 16; ++i) {
      const int node = nb0 + w * 16 + i;
      float s0 = 0.f, s1v = 0.f;
      float m0 = -__builtin_inff(), m1 = -__builtin_inff();
      if (node < NN) {
        const int sidx = roff[node], eidx = roff[node + 1];
        int ix = sidx;
        for (; ix + 1 < eidx; ix += 2) {
          const int ea = elist[ix], eb = elist[ix + 1];
          const float* pa = half ? (upd + (size_t)ea * ED + c2) : (nf + (size_t)src[ea] * ND + c2);
          const float* pb = half ? (upd + (size_t)eb * ED + c2) : (nf + (size_t)src[eb] * ND + c2);
          const float a0 = pa[0], a1 = pa[1], c0 = pb[0], c1 = pb[1];
          s0 += a0 + c0; s1v += a1 + c1;
          m0 = fmaxf(m0, fmaxf(a0, c0)); m1 = fmaxf(m1, fmaxf(a1, c1));
        }
        if (ix < eidx) {
          const int ea = elist[ix];
          const float* pa = half ? (upd + (size_t)ea * ED + c2) : (nf + (size_t)src[ea] * ND + c2);
          const float a0 = pa[0], a1 = pa[1];
          s0 += a0; s1v += a1;
          m0 = fmaxf(m0, a0); m1 = fmaxf(m1, a1);
        }
        if (sidx == eidx) { m0 = 0.f; m1 = 0.f; }
      } else {
        m0 = 0.f; m1 = 0.f;
      }
      const int cs = half * 64 + c2;
      win[i * 256 + cs] = s0;
      win[i * 256 + cs + 1] = s1v;
      win[i * 256 + 128 + cs] = m0;
      win[i * 256 + 128 + cs + 1] = m1;
    }
  }
  __syncthreads();

  const int quad = lane >> 4, lc = lane & 15;
  const f32x4 vzero = {0.f, 0.f, 0.f, 0.f};

  // GEMM1: y = agg(K=256) @ W1n^T + b1 -> LN -> leaky(0.2) -> window @ stride AS
  s16x8 ah8[8], al8[8];
#pragma unroll
  for (int ks = 0; ks < 8; ++ks) split8(&win[lc * 256 + ks * 32 + quad * 8], ah8[ks], al8[ks]);
  f32x4 acc[12];
#pragma unroll
  for (int nt = 0; nt < 12; ++nt) acc[nt] = vzero;
  gemm3p<12, 8>(acc, ah8, al8, pW1, lane);
  {
    float s1[4] = {0, 0, 0, 0}, s2[4] = {0, 0, 0, 0};
#pragma unroll
    for (int nt = 0; nt < 12; ++nt) {
      const float bb = b1[nt * 16 + lc];
#pragma unroll
      for (int r = 0; r < 4; ++r) {
        const float v = acc[nt][r] + bb;
        acc[nt][r] = v; s1[r] += v; s2[r] += v * v;
      }
    }
#pragma unroll
    for (int r = 0; r < 4; ++r) {
#pragma unroll
      for (int m = 1; m < 16; m <<= 1) {
        s1[r] += __shfl_xor(s1[r], m, 16);
        s2[r] += __shfl_xor(s2[r], m, 16);
      }
      const float mu = s1[r] * (1.f / 192.f);
      const float va = s2[r] * (1.f / 192.f) - mu * mu;
      s1[r] = mu; s2[r] = rsqrtf(va + 1e-5f);
    }
#pragma unroll
    for (int nt = 0; nt < 12; ++nt) {
      const int col = nt * 16 + lc;
      const float g = lng[col], be = lnb[col];
#pragma unroll
      for (int r = 0; r < 4; ++r) {
        float v = (acc[nt][r] - s1[r]) * s2[r] * g + be;
        v = v > 0.f ? v : 0.2f * v;
        win[(quad * 4 + r) * AS + col] = v;
      }
    }
  }
  __syncthreads();

  // Fused GEMM (was GEMM2+GEMM3): gi = y @ Wfuse_a^T ; rz fused with h-side, ni/nh separate.
  s16x8 ah[6], al[6];
#pragma unroll
  for (int ks = 0; ks < 6; ++ks) split8(&win[lc * AS + ks * 32 + quad * 8], ah[ks], al[ks]);
  f32x4 rz[8], ni[4], nh[4], ro[4];
#pragma unroll
  for (int nt = 0; nt < 8; ++nt) rz[nt] = vzero;
#pragma unroll
  for (int nt = 0; nt < 4; ++nt) { ni[nt] = vzero; nh[nt] = vzero; ro[nt] = vzero; }
  gemm3p<8, 6, 12>(rz, ah, al, pWih, lane);
  gemm3p<4, 6, 12>(ni, ah, al, pWih + 8 * 6 * 512, lane);

  s16x8 hh[2], hl[2];
  {
    const int gr = nb0 + w * 16 + lc;
    const float* hp = nf + (size_t)(gr < NN ? gr : NN - 1) * ND;
#pragma unroll
    for (int ks = 0; ks < 2; ++ks) split8(hp + ks * 32 + quad * 8, hh[ks], hl[ks]);
  }
  gemm3p<8, 2, 12>(rz, hh, hl, pWhh, lane);
  gemm3p<4, 2, 12>(nh, hh, hl, pWhh + 8 * 2 * 512, lane);
  gemm3p<4, 2>(ro, hh, hl, pWra, lane);

  // GRU + residual + leaky(0.01) -> update_nodes (bfz = bih + Wih@b2)
#pragma unroll
  for (int nt = 0; nt < 4; ++nt) {
    const int col = nt * 16 + lc;
    const float bir = bfz[col], biz = bfz[64 + col], bin = bfz[128 + col];
    const float bhr = bhh[col], bhz = bhh[64 + col], bhn = bhh[128 + col];
    const float br = bra[col];
#pragma unroll
    for (int r = 0; r < 4; ++r) {
      const int node = nb0 + w * 16 + quad * 4 + r;
      if (node < NN) {
        const float h = nf[(size_t)node * ND + col];
        const float rg = fsigmoid(rz[nt][r] + bir + bhr);
        const float zg = fsigmoid(rz[nt + 4][r] + biz + bhz);
        const float ng = ftanh(ni[nt][r] + bin + rg * (nh[nt][r] + bhn));
        float v = (1.f - zg) * ng + zg * h + ro[nt][r] + br;
        v = v > 0.f ? v : 0.01f * v;
        outn[(size_t)node * ND + col] = v;
      }
    }
  }
}

// ---------- launch ----------
extern "C" void kernel_launch(void* const* d_in, const int* in_sizes, int n_in,
                              void* d_out, int out_size, void* d_ws, size_t ws_size,
                              hipStream_t stream) {
  (void)in_sizes; (void)n_in; (void)out_size; (void)ws_size;
  const float* nf    = (const float*)d_in[0];
  const float* ef    = (const float*)d_in[1];
  const int*   src   = (const int*)d_in[2];
  const int*   dst   = (const int*)d_in[3];
  const float* W1e   = (const float*)d_in[4];
  const float* W1n   = (const float*)d_in[5];
  const float* b1    = (const float*)d_in[6];
  const float* lng   = (const float*)d_in[7];
  const float* lnb   = (const float*)d_in[8];
  const float* W2    = (const float*)d_in[9];
  const float* b2    = (const float*)d_in[10];
  const float* Wih_e = (const float*)d_in[11];
  const float* Whh_e = (const float*)d_in[12];
  const float* bih_e = (const float*)d_in[13];
  const float* bhh_e = (const float*)d_in[14];
  const float* Wih_a = (const float*)d_in[15];
  const float* Whh_a = (const float*)d_in[16];
  const float* bih_a = (const float*)d_in[17];
  const float* bhh_a = (const float*)d_in[18];
  const float* Wre   = (const float*)d_in[19];
  const float* bre   = (const float*)d_in[20];
  const float* Wra   = (const float*)d_in[21];
  const float* bra   = (const float*)d_in[22];

  // workspace layout (bytes)
  unsigned short* packs = (unsigned short*)d_ws;        // 917,504 B
  char* base = (char*)d_ws;
  int* cnt    = (int*)(base + 917504);                  // NN ints
  int* roff   = (int*)(base + 1117504);                 // NN+1 ints
  int* cursor = (int*)(base + 1317512);                 // NN ints (reused for fused biases)
  int* elist  = (int*)(base + 1517512);                 // EE ints
  float* bfused = (float*)cursor;                       // bf[0:192]=edge, bf[192:384]=node

  constexpr int OFF_W1e = 0, OFF_W1n = 73728,
                OFF_Wihe = 245760, OFF_Whhe = 319488, OFF_Wre = 344064,
                OFF_Wiha = 352256, OFF_Whha = 425984, OFF_Wra = 450560;

  float* out_nodes = (float*)d_out;
  float* out_edges = out_nodes + (size_t)NN * ND;

  k_pack<<<896, 256, 0, stream>>>(W1e, W1n, W2, Wih_e, Whh_e, Wre, Wih_a, Whh_a, Wra, packs);
  k_packfuse<<<288, 256, 0, stream>>>(W2, Wih_e, Wih_a, packs);  // overwrites Wihe/Wiha slots
  k_zero<<<(NN + 255) / 256, 256, 0, stream>>>(cnt);
  k_hist<<<(EE + 255) / 256, 256, 0, stream>>>(dst, cnt);
  k_scan<<<1, 1024, 0, stream>>>(cnt, roff, cursor);
  k_scatter<<<(EE + 255) / 256, 256, 0, stream>>>(dst, cursor, elist);
  k_fusebias<<<1, 384, 0, stream>>>(Wih_e, Wih_a, b2, bih_e, bih_a, bfused);  // cursor now dead

  edge_kernel<<<EE / 64, 256, 0, stream>>>(
      nf, ef, src, dst, b1, lng, lnb, bfused, bhh_e, bre,
      packs + OFF_W1e, packs + OFF_Wihe, packs + OFF_Whhe, packs + OFF_Wre,
      out_edges);

  node_kernel<<<(NN + 63) / 64, 256, 0, stream>>>(
      nf, src, roff, elist, b1, lng, lnb, bfused + 192, bhh_a, bra,
      packs + OFF_W1n, packs + OFF_Wiha, packs + OFF_Whha, packs + OFF_Wra,
      out_edges, out_nodes);
}